// Round 2
// baseline (75.906 us; speedup 1.0000x reference)
//
#include <hip/hip_runtime.h>
#include <math.h>

// z_q[b] = r^T A_q r with r = (c0,s0)(x)(c1,s1), c_i=cos(x_i*pi/2), s_i=sin(x_i*pi/2).
// Double-angle: quadratic monomials in (c,s) are linear in (1, cos(pi x), sin(pi x)):
//   c^2=(1+C)/2, s^2=(1-C)/2, cs=S/2.
// So z_q = e0^T K_q e1, e_i=(1, cos(pi x_i), sin(pi x_i)), K_q 3x3 from weights only.
// Every thread computes K0,K1 redundantly (fully unrolled, fast sincos, ~250 ops);
// no LDS, no __syncthreads, no serial thread-0 section.

struct Cx { float re, im; };
__device__ inline Cx cmul(Cx a, Cx b){ return {a.re*b.re - a.im*b.im, a.re*b.im + a.im*b.re}; }
__device__ inline Cx cmadd2(Cx a, Cx x, Cx b, Cx y){
  Cx p = cmul(a,x), q = cmul(b,y);
  return { p.re + q.re, p.im + q.im };
}

#define PI_F 3.14159265358979323846f

__global__ __launch_bounds__(256) void qc_kernel(const float* __restrict__ noise,
                                                 const float* __restrict__ w,
                                                 float* __restrict__ out,
                                                 int nQuads) {
  // ---- preamble: K0,K1 from the 12 weights (identical math to validated R0) ----
  Cx U[4][4];
  #pragma unroll
  for (int r = 0; r < 4; ++r)
    #pragma unroll
    for (int c = 0; c < 4; ++c)
      U[r][c] = { (r == c) ? 1.f : 0.f, 0.f };

  #pragma unroll
  for (int l = 0; l < 2; ++l) {
    Cx g[2][2][2];
    #pragma unroll
    for (int q = 0; q < 2; ++q) {
      float phi = w[l*6 + q*3 + 0];
      float th  = w[l*6 + q*3 + 1];
      float om  = w[l*6 + q*3 + 2];
      float st, ct; __sincosf(0.5f*th, &st, &ct);
      float sp, cp; __sincosf(0.5f*(phi+om), &sp, &cp);
      float sm, cm; __sincosf(0.5f*(phi-om), &sm, &cm);
      g[q][0][0] = {  cp*ct, -sp*ct };
      g[q][0][1] = { -cm*st, -sm*st };
      g[q][1][0] = {  cm*st, -sm*st };
      g[q][1][1] = {  cp*ct,  sp*ct };
    }
    #pragma unroll
    for (int c = 0; c < 4; ++c)
      #pragma unroll
      for (int k = 0; k < 2; ++k) {
        Cx x0 = U[k][c], x1 = U[2+k][c];
        U[k][c]   = cmadd2(g[0][0][0], x0, g[0][0][1], x1);
        U[2+k][c] = cmadd2(g[0][1][0], x0, g[0][1][1], x1);
      }
    #pragma unroll
    for (int c = 0; c < 4; ++c)
      #pragma unroll
      for (int j = 0; j < 2; ++j) {
        Cx x0 = U[2*j][c], x1 = U[2*j+1][c];
        U[2*j][c]   = cmadd2(g[1][0][0], x0, g[1][0][1], x1);
        U[2*j+1][c] = cmadd2(g[1][1][0], x0, g[1][1][1], x1);
      }
    #pragma unroll
    for (int c = 0; c < 4; ++c) { Cx t = U[2][c]; U[2][c] = U[3][c]; U[3][c] = t; }
    #pragma unroll
    for (int c = 0; c < 4; ++c) { Cx t = U[1][c]; U[1][c] = U[3][c]; U[3][c] = t; }
  }

  // V = U*D, D=diag(1,-i,-i,-1)
  #pragma unroll
  for (int r = 0; r < 4; ++r) {
    Cx t;
    t = U[r][1]; U[r][1] = {  t.im, -t.re };
    t = U[r][2]; U[r][2] = {  t.im, -t.re };
    t = U[r][3]; U[r][3] = { -t.re, -t.im };
  }

  // A_q[a][b] = sum_r zq[r] Re(conj(V[r][a]) V[r][b])
  float A0f[16], A1f[16];
  {
    const float z0s[4] = { 1.f,  1.f, -1.f, -1.f };
    const float z1s[4] = { 1.f, -1.f,  1.f, -1.f };
    #pragma unroll
    for (int a = 0; a < 4; ++a)
      #pragma unroll
      for (int b = 0; b < 4; ++b) {
        float a0 = 0.f, a1 = 0.f;
        #pragma unroll
        for (int r = 0; r < 4; ++r) {
          float d = U[r][a].re*U[r][b].re + U[r][a].im*U[r][b].im;
          a0 += z0s[r]*d;
          a1 += z1s[r]*d;
        }
        A0f[a*4+b] = a0;
        A1f[a*4+b] = a1;
      }
  }

  // K_q[p][qq] = sum_{i,k,j,l} A_q[2i+j][2k+l] t[i][k][p] t[j][l][qq]
  // t[0][0]=(.5,.5,0) t[0][1]=t[1][0]=(0,0,.5) t[1][1]=(.5,-.5,0) — constants fold.
  float K0[3][3] = {}, K1[3][3] = {};
  {
    const float t00[3] = {0.5f, 0.5f, 0.f};
    const float t01[3] = {0.f,  0.f,  0.5f};
    const float t11[3] = {0.5f,-0.5f, 0.f};
    const float* tv[2][2] = { { t00, t01 }, { t01, t11 } };
    #pragma unroll
    for (int i = 0; i < 2; ++i)
      #pragma unroll
      for (int j = 0; j < 2; ++j)
        #pragma unroll
        for (int k = 0; k < 2; ++k)
          #pragma unroll
          for (int l = 0; l < 2; ++l) {
            float a0 = A0f[(2*i+j)*4 + (2*k+l)];
            float a1 = A1f[(2*i+j)*4 + (2*k+l)];
            #pragma unroll
            for (int p = 0; p < 3; ++p) {
              float tp = tv[i][k][p];
              if (tp == 0.f) continue;  // compile-time folded
              #pragma unroll
              for (int qq = 0; qq < 3; ++qq) {
                float tq = tv[j][l][qq];
                K0[p][qq] += a0 * tp * tq;
                K1[p][qq] += a1 * tp * tq;
              }
            }
          }
  }

  // ---- streaming main loop: 2 sincos + 16 FMA per sample ----
  const float4* __restrict__ in4 = (const float4*)noise;
  float4* __restrict__ out4 = (float4*)out;

  int gid    = blockIdx.x * blockDim.x + threadIdx.x;
  int stride = gridDim.x * blockDim.x;

  auto zpair = [&](float x0, float x1, float& z0, float& z1) {
    float S0, C0, S1, C1;
    __sincosf(x0 * PI_F, &S0, &C0);
    __sincosf(x1 * PI_F, &S1, &C1);
    float m00 = K0[0][0] + K0[0][1]*C1 + K0[0][2]*S1;
    float m01 = K0[1][0] + K0[1][1]*C1 + K0[1][2]*S1;
    float m02 = K0[2][0] + K0[2][1]*C1 + K0[2][2]*S1;
    z0 = m00 + m01*C0 + m02*S0;
    float m10 = K1[0][0] + K1[0][1]*C1 + K1[0][2]*S1;
    float m11 = K1[1][0] + K1[1][1]*C1 + K1[1][2]*S1;
    float m12 = K1[2][0] + K1[2][1]*C1 + K1[2][2]*S1;
    z1 = m10 + m11*C0 + m12*S0;
  };

  if (gid + 3*stride < nQuads) {
    // exact-fit fast path: 4 loads in flight, then compute+store
    float4 v0 = in4[gid];
    float4 v1 = in4[gid +   stride];
    float4 v2 = in4[gid + 2*stride];
    float4 v3 = in4[gid + 3*stride];
    float4 o;
    zpair(v0.x, v0.y, o.x, o.y); zpair(v0.z, v0.w, o.z, o.w); out4[gid]            = o;
    zpair(v1.x, v1.y, o.x, o.y); zpair(v1.z, v1.w, o.z, o.w); out4[gid +   stride] = o;
    zpair(v2.x, v2.y, o.x, o.y); zpair(v2.z, v2.w, o.z, o.w); out4[gid + 2*stride] = o;
    zpair(v3.x, v3.y, o.x, o.y); zpair(v3.z, v3.w, o.z, o.w); out4[gid + 3*stride] = o;
  } else {
    for (int i = gid; i < nQuads; i += stride) {
      float4 v = in4[i];
      float4 o;
      zpair(v.x, v.y, o.x, o.y);
      zpair(v.z, v.w, o.z, o.w);
      out4[i] = o;
    }
  }
}

extern "C" void kernel_launch(void* const* d_in, const int* in_sizes, int n_in,
                              void* d_out, int out_size, void* d_ws, size_t ws_size,
                              hipStream_t stream) {
  const float* noise = (const float*)d_in[0];   // [B,2] float32
  const float* w     = (const float*)d_in[1];   // [2,2,3] float32
  float* out         = (float*)d_out;           // [B,2] float32

  int nQuads = in_sizes[0] / 4;  // B*2 floats -> B/2 float4 chunks
  qc_kernel<<<1024, 256, 0, stream>>>(noise, w, out, nQuads);
}